// Round 2
// baseline (510.009 us; speedup 1.0000x reference)
//
#include <hip/hip_runtime.h>
#include <hip/hip_bf16.h>

#define B_  4
#define S_  2048
#define E_  1024
#define H_  16
#define DH_ 64
#define M_  (B_*S_)    // 8192 rows
#define HD_ (H_*DH_)   // 1024

typedef unsigned short u16;
typedef __attribute__((ext_vector_type(8))) __bf16 bf16x8;
typedef __attribute__((ext_vector_type(4))) __bf16 bf16x4;
typedef __attribute__((ext_vector_type(4))) float  f32x4;

#if __has_builtin(__builtin_amdgcn_exp2f)
#define EXP2F __builtin_amdgcn_exp2f
#else
#define EXP2F __builtin_exp2f
#endif

// scale folded into Q at QKV epilogue: 1/sqrt(64) * log2(e)
#define QSCALE 0.18033688011112042f

// ---- async global->LDS, 16B per lane ----
__device__ __forceinline__ void g2l16(const void* g, void* l) {
  __builtin_amdgcn_global_load_lds(
      (const __attribute__((address_space(1))) void*)g,
      (__attribute__((address_space(3))) void*)l, 16, 0, 0);
}

// RNE float -> bf16 bits
__device__ __forceinline__ u16 f2bf(float f) {
  union { float f; unsigned u; } v; v.f = f;
  unsigned r = v.u + 0x7FFFu + ((v.u >> 16) & 1u);
  return (u16)(r >> 16);
}

// ---------------- conversion / packing kernels ----------------
__global__ __launch_bounds__(256) void cvt_x_kernel(const float* __restrict__ x,
                                                    u16* __restrict__ xb) {
  int i = blockIdx.x * 256 + threadIdx.x;
  float4 v = ((const float4*)x)[i];
  ushort4 o;
  o.x = f2bf(v.x); o.y = f2bf(v.y); o.z = f2bf(v.z); o.w = f2bf(v.w);
  ((ushort4*)xb)[i] = o;
}

__global__ __launch_bounds__(256) void pack_wqkv_kernel(
    const float* __restrict__ Wq, const float* __restrict__ Wk,
    const float* __restrict__ Wv, u16* __restrict__ wt) {
  __shared__ u16 tile[64][66];
  int p = blockIdx.z, h = blockIdx.y, e0 = blockIdx.x * 64;
  const float* src = (p == 0 ? Wq : (p == 1 ? Wk : Wv)) + h * (E_ * DH_);
  int tid = threadIdx.x;
#pragma unroll
  for (int r = 0; r < 16; ++r) {
    int idx = r * 256 + tid;
    int el = idx >> 6, d = idx & 63;
    tile[el][d] = f2bf(src[(e0 + el) * DH_ + d]);
  }
  __syncthreads();
  u16* dst = wt + (p * HD_ + h * DH_) * E_;
#pragma unroll
  for (int r = 0; r < 16; ++r) {
    int idx = r * 256 + tid;
    int d = idx >> 6, el = idx & 63;
    dst[d * E_ + e0 + el] = tile[el][d];
  }
}

__global__ __launch_bounds__(256) void pack_wo_kernel(const float* __restrict__ Wo,
                                                      u16* __restrict__ wt) {
  __shared__ u16 tile[64][66];
  int c0 = blockIdx.y * 64, e0 = blockIdx.x * 64;
  int tid = threadIdx.x;
#pragma unroll
  for (int r = 0; r < 16; ++r) {
    int idx = r * 256 + tid;
    int cl = idx >> 6, el = idx & 63;
    tile[cl][el] = f2bf(Wo[(c0 + cl) * E_ + e0 + el]);
  }
  __syncthreads();
#pragma unroll
  for (int r = 0; r < 16; ++r) {
    int idx = r * 256 + tid;
    int er = idx >> 6, cl = idx & 63;
    wt[(e0 + er) * HD_ + c0 + cl] = tile[cl][er];
  }
}

__global__ __launch_bounds__(256) void pack_bias_kernel(
    const float* __restrict__ bq, const float* __restrict__ bk,
    const float* __restrict__ bv, float* __restrict__ bb) {
  int i = blockIdx.x * 256 + threadIdx.x;
  const float* s = (i < 1024 ? bq : (i < 2048 ? bk : bv));
  bb[i] = s[i & 1023];
}

// ---------------- GEMM: C[M][N] = A[M][K] * Bt[N][K]^T, K = 1024 ----------------
template <int MODE>
__global__ __launch_bounds__(256) void gemm_bt_kernel(
    const u16* __restrict__ A, const u16* __restrict__ Bt,
    const float* __restrict__ bias,
    u16* __restrict__ oQ, u16* __restrict__ oK, u16* __restrict__ oV,
    float* __restrict__ oF) {
  constexpr int K = 1024;
  __shared__ __align__(16) u16 As[128 * 32];
  __shared__ __align__(16) u16 Bs[128 * 32];
  const int tid = threadIdx.x;
  const int lane = tid & 63, wv = tid >> 6;
  const int wm = (wv >> 1) * 64, wn = (wv & 1) * 64;
  const int q4 = lane >> 4, lm = lane & 15;
  const int tileM = blockIdx.y * 128, tileN = blockIdx.x * 128;

  const int c0 = tid, c1 = tid + 256;
  const u16* gA0 = A + (tileM + (c0 >> 2)) * K + (((c0 & 3) ^ ((c0 >> 2) & 3)) * 8);
  const u16* gA1 = A + (tileM + (c1 >> 2)) * K + (((c1 & 3) ^ ((c1 >> 2) & 3)) * 8);
  const u16* gB0 = Bt + (tileN + (c0 >> 2)) * K + (((c0 & 3) ^ ((c0 >> 2) & 3)) * 8);
  const u16* gB1 = Bt + (tileN + (c1 >> 2)) * K + (((c1 & 3) ^ ((c1 >> 2) & 3)) * 8);
  u16* lA0 = As + c0 * 8; u16* lA1 = As + c1 * 8;
  u16* lB0 = Bs + c0 * 8; u16* lB1 = Bs + c1 * 8;

  f32x4 acc[4][4] = {};

  int aoff[4], boff[4];
#pragma unroll
  for (int i = 0; i < 4; ++i) {
    int ra = wm + i * 16 + lm;
    aoff[i] = ra * 32 + ((q4 ^ (ra & 3)) * 8);
    int rb = wn + i * 16 + lm;
    boff[i] = rb * 32 + ((q4 ^ (rb & 3)) * 8);
  }

  for (int k0 = 0; k0 < K; k0 += 32) {
    g2l16(gA0 + k0, lA0);
    g2l16(gA1 + k0, lA1);
    g2l16(gB0 + k0, lB0);
    g2l16(gB1 + k0, lB1);
    __syncthreads();
    bf16x8 af[4], bf[4];
#pragma unroll
    for (int i = 0; i < 4; ++i) af[i] = *(const bf16x8*)(As + aoff[i]);
#pragma unroll
    for (int j = 0; j < 4; ++j) bf[j] = *(const bf16x8*)(Bs + boff[j]);
#pragma unroll
    for (int i = 0; i < 4; ++i)
#pragma unroll
      for (int j = 0; j < 4; ++j)
        acc[i][j] = __builtin_amdgcn_mfma_f32_16x16x32_bf16(af[i], bf[j], acc[i][j], 0, 0, 0);
    __syncthreads();
  }

#pragma unroll
  for (int j = 0; j < 4; ++j) {
    int n = tileN + wn + j * 16 + lm;
    float bs = bias[n];
#pragma unroll
    for (int i = 0; i < 4; ++i) {
#pragma unroll
      for (int r = 0; r < 4; ++r) {
        int m = tileM + wm + i * 16 + q4 * 4 + r;
        float val = acc[i][j][r] + bs;
        if (MODE == 1) {
          oF[m * HD_ + n] = val;
        } else {
          int proj = n >> 10, cc = n & 1023;   // uniform per block
          if (proj == 0) {
            oQ[m * 1024 + cc] = f2bf(val * QSCALE);   // fold softmax scale+log2e into Q
          } else if (proj == 1) {
            oK[m * 1024 + cc] = f2bf(val);
          } else {
            int bb = m >> 11, ss = m & 2047, hh = cc >> 6, dd = cc & 63;
            oV[((bb * H_ + hh) * DH_ + dd) * S_ + ss] = f2bf(val);   // V^T [b,h,d,s]
          }
        }
      }
    }
  }
}

// ---------------- flash attention (no-max softmax, S^T trick, barrier-free loop) ----
// Block: 64 Q rows for one (b,h). 4 waves; wave w owns key-tiles [w*8, w*8+8).
// K/V/Q frags loaded global->VGPR directly. P transits wave-private LDS.
// li computed by MFMA with ones B-operand. Cross-wave combine via LDS atomics.
__global__ __launch_bounds__(256, 2) void flash_kernel(
    const u16* __restrict__ Q, const u16* __restrict__ Kb,
    const u16* __restrict__ Vt, u16* __restrict__ Z) {
  __shared__ __align__(16) u16 Ps[4][64 * 64];   // per-wave P
  __shared__ float Osum[64 * 65];
  __shared__ float liS[64];
  const int tid = threadIdx.x, lane = tid & 63, wv = tid >> 6;
  const int q4 = lane >> 4, lm = lane & 15;

  // XCD swizzle: 32 consecutive blocks on one XCD share one (b,h)'s K/V
  const int bid = blockIdx.x;
  const int xcd = bid & 7, seq = bid >> 3;
  const int bh = xcd * 8 + (seq >> 5), qt = seq & 31;
  const int b = bh >> 4, h = bh & 15;

  const u16* qbase = Q + ((size_t)(b * S_ + qt * 64)) * HD_ + h * DH_;
  const u16* kbase = Kb + (size_t)b * S_ * HD_ + h * DH_;
  const u16* vbase = Vt + ((size_t)(b * H_ + h)) * DH_ * S_;
  u16* zbase = Z + ((size_t)(b * S_ + qt * 64)) * HD_ + h * DH_;

  // zero reduction buffers
  for (int i = tid; i < 64 * 65; i += 256) Osum[i] = 0.f;
  if (tid < 64) liS[tid] = 0.f;
  __syncthreads();

  // Q B-frags (persistent): Q[qrow][dim], qrow=qb*16+lm, dim=dc*32+q4*8..+7
  bf16x8 qf[4][2];
#pragma unroll
  for (int qb = 0; qb < 4; ++qb)
#pragma unroll
    for (int dc = 0; dc < 2; ++dc)
      qf[qb][dc] = *(const bf16x8*)(qbase + (qb * 16 + lm) * HD_ + dc * 32 + q4 * 8);

  const bf16x8 ones = {(__bf16)1.f, (__bf16)1.f, (__bf16)1.f, (__bf16)1.f,
                       (__bf16)1.f, (__bf16)1.f, (__bf16)1.f, (__bf16)1.f};

  f32x4 oacc[4][4] = {};
  f32x4 liacc[4] = {};
  u16* Pw = Ps[wv];

  for (int ti = 0; ti < 8; ++ti) {
    const int t = wv * 8 + ti;
    const u16* kt = kbase + (size_t)t * 64 * HD_;
    const u16* vt = vbase + t * 64;

    // ---- S^T = K*Q^T, 32 keys per chunk; exp2; pack to P LDS ----
#pragma unroll
    for (int ck = 0; ck < 2; ++ck) {
      bf16x8 kf[2][2];
#pragma unroll
      for (int kb = 0; kb < 2; ++kb)
#pragma unroll
        for (int dc = 0; dc < 2; ++dc)
          kf[kb][dc] = *(const bf16x8*)(kt + (ck * 32 + kb * 16 + lm) * HD_ + dc * 32 + q4 * 8);
#pragma unroll
      for (int qb = 0; qb < 4; ++qb) {
#pragma unroll
        for (int kb = 0; kb < 2; ++kb) {
          f32x4 sc = {};
          sc = __builtin_amdgcn_mfma_f32_16x16x32_bf16(kf[kb][0], qf[qb][0], sc, 0, 0, 0);
          sc = __builtin_amdgcn_mfma_f32_16x16x32_bf16(kf[kb][1], qf[qb][1], sc, 0, 0, 0);
          f32x4 p;
#pragma unroll
          for (int r = 0; r < 4; ++r) p[r] = EXP2F(sc[r]);
          bf16x4 pb = __builtin_convertvector(p, bf16x4);
          // C/D of S^T: row=key=ck*32+kb*16+q4*4+r, col=qrow=qb*16+lm
          int key0 = ck * 32 + kb * 16 + q4 * 4;      // 4 consecutive keys
          int qrow = qb * 16 + lm;
          int c8 = key0 >> 3;
          int off = qrow * 64 + ((c8 ^ (qrow & 7)) * 8) + (key0 & 7);
          *(bf16x4*)(Pw + off) = pb;                  // ds_write_b64
        }
      }
    }

    asm volatile("s_waitcnt lgkmcnt(0)" ::: "memory");   // P writes visible to this wave

    // ---- O += P * V^T ; li += P * ones ----
#pragma unroll
    for (int ck = 0; ck < 2; ++ck) {
      bf16x8 pf[4];
#pragma unroll
      for (int qb = 0; qb < 4; ++qb) {
        int qrow = qb * 16 + lm;
        int c8 = ck * 4 + q4;
        pf[qb] = *(const bf16x8*)(Pw + qrow * 64 + ((c8 ^ (qrow & 7)) * 8));
      }
      bf16x8 vf[4];
#pragma unroll
      for (int db = 0; db < 4; ++db)
        vf[db] = *(const bf16x8*)(vt + (db * 16 + lm) * S_ + ck * 32 + q4 * 8);
#pragma unroll
      for (int qb = 0; qb < 4; ++qb)
        liacc[qb] = __builtin_amdgcn_mfma_f32_16x16x32_bf16(pf[qb], ones, liacc[qb], 0, 0, 0);
#pragma unroll
      for (int qb = 0; qb < 4; ++qb)
#pragma unroll
        for (int db = 0; db < 4; ++db)
          oacc[qb][db] = __builtin_amdgcn_mfma_f32_16x16x32_bf16(pf[qb], vf[db], oacc[qb][db], 0, 0, 0);
    }
  }

  // ---- cross-wave combine ----
#pragma unroll
  for (int qb = 0; qb < 4; ++qb)
#pragma unroll
    for (int db = 0; db < 4; ++db)
#pragma unroll
      for (int r = 0; r < 4; ++r)
        atomicAdd(&Osum[(qb * 16 + q4 * 4 + r) * 65 + db * 16 + lm], oacc[qb][db][r]);
  if (lm == 0) {
#pragma unroll
    for (int qb = 0; qb < 4; ++qb)
#pragma unroll
      for (int r = 0; r < 4; ++r)
        atomicAdd(&liS[qb * 16 + q4 * 4 + r], liacc[qb][r]);
  }
  __syncthreads();

  // ---- normalize + store ----
  {
    int row = tid >> 2, cg = (tid & 3) * 16;
    float rin = 1.f / liS[row];
    u16* zp = zbase + row * HD_ + cg;
#pragma unroll
    for (int half = 0; half < 2; ++half) {
      f32x4 a, c;
#pragma unroll
      for (int r = 0; r < 4; ++r) a[r] = Osum[row * 65 + cg + half * 8 + r] * rin;
#pragma unroll
      for (int r = 0; r < 4; ++r) c[r] = Osum[row * 65 + cg + half * 8 + 4 + r] * rin;
      bf16x4 ab = __builtin_convertvector(a, bf16x4);
      bf16x4 cb = __builtin_convertvector(c, bf16x4);
      *(bf16x4*)(zp + half * 8) = ab;
      *(bf16x4*)(zp + half * 8 + 4) = cb;
    }
  }
}

// ---------------- host ----------------
extern "C" void kernel_launch(void* const* d_in, const int* in_sizes, int n_in,
                              void* d_out, int out_size, void* d_ws, size_t ws_size,
                              hipStream_t stream) {
  const float* x  = (const float*)d_in[0];
  const float* Wq = (const float*)d_in[1];
  const float* bq = (const float*)d_in[2];
  const float* Wk = (const float*)d_in[3];
  const float* bk = (const float*)d_in[4];
  const float* Wv = (const float*)d_in[5];
  const float* bv = (const float*)d_in[6];
  const float* Wo = (const float*)d_in[7];
  const float* bo = (const float*)d_in[8];
  float* out = (float*)d_out;

  char* w = (char*)d_ws;
  u16*   xb    = (u16*)w;   w += (size_t)M_ * E_ * 2;
  u16*   wqkvT = (u16*)w;   w += (size_t)3 * HD_ * E_ * 2;
  u16*   woT   = (u16*)w;   w += (size_t)E_ * HD_ * 2;
  float* bqkv  = (float*)w; w += (size_t)3 * HD_ * 4;
  u16*   qB    = (u16*)w;   w += (size_t)M_ * HD_ * 2;
  u16*   kB    = (u16*)w;   w += (size_t)M_ * HD_ * 2;
  u16*   vT    = (u16*)w;   w += (size_t)M_ * HD_ * 2;
  u16*   zB    = (u16*)w;   w += (size_t)M_ * HD_ * 2;

  cvt_x_kernel<<<dim3(M_ * E_ / 4 / 256), 256, 0, stream>>>(x, xb);
  pack_wqkv_kernel<<<dim3(16, 16, 3), 256, 0, stream>>>(Wq, Wk, Wv, wqkvT);
  pack_wo_kernel<<<dim3(16, 16), 256, 0, stream>>>(Wo, woT);
  pack_bias_kernel<<<dim3(12), 256, 0, stream>>>(bq, bk, bv, bqkv);
  gemm_bt_kernel<0><<<dim3(24, 64), 256, 0, stream>>>(xb, wqkvT, bqkv, qB, kB, vT, nullptr);
  flash_kernel<<<dim3(2048), 256, 0, stream>>>(qB, kB, vT, zB);
  gemm_bt_kernel<1><<<dim3(8, 64), 256, 0, stream>>>(zB, woT, bo, nullptr, nullptr, nullptr, out);
}

// Round 3
// 323.993 us; speedup vs baseline: 1.5741x; 1.5741x over previous
//
#include <hip/hip_runtime.h>
#include <hip/hip_bf16.h>

#define B_  4
#define S_  2048
#define E_  1024
#define H_  16
#define DH_ 64
#define M_  (B_*S_)    // 8192 rows
#define HD_ (H_*DH_)   // 1024

typedef unsigned short u16;
typedef __attribute__((ext_vector_type(8))) __bf16 bf16x8;
typedef __attribute__((ext_vector_type(4))) __bf16 bf16x4;
typedef __attribute__((ext_vector_type(4))) float  f32x4;

#if __has_builtin(__builtin_amdgcn_exp2f)
#define EXP2F __builtin_amdgcn_exp2f
#else
#define EXP2F __builtin_exp2f
#endif

// softmax scale folded into Q at QKV epilogue: 1/sqrt(64) * log2(e)
#define QSCALE 0.18033688011112042f

// ---- async global->LDS, 16B per lane ----
__device__ __forceinline__ void g2l16(const void* g, void* l) {
  __builtin_amdgcn_global_load_lds(
      (const __attribute__((address_space(1))) void*)g,
      (__attribute__((address_space(3))) void*)l, 16, 0, 0);
}

// RNE float -> bf16 bits
__device__ __forceinline__ u16 f2bf(float f) {
  union { float f; unsigned u; } v; v.f = f;
  unsigned r = v.u + 0x7FFFu + ((v.u >> 16) & 1u);
  return (u16)(r >> 16);
}

// ---------------- conversion / packing kernels ----------------
__global__ __launch_bounds__(256) void cvt_x_kernel(const float* __restrict__ x,
                                                    u16* __restrict__ xb) {
  int i = blockIdx.x * 256 + threadIdx.x;
  float4 v = ((const float4*)x)[i];
  ushort4 o;
  o.x = f2bf(v.x); o.y = f2bf(v.y); o.z = f2bf(v.z); o.w = f2bf(v.w);
  ((ushort4*)xb)[i] = o;
}

__global__ __launch_bounds__(256) void pack_wqkv_kernel(
    const float* __restrict__ Wq, const float* __restrict__ Wk,
    const float* __restrict__ Wv, u16* __restrict__ wt) {
  __shared__ u16 tile[64][66];
  int p = blockIdx.z, h = blockIdx.y, e0 = blockIdx.x * 64;
  const float* src = (p == 0 ? Wq : (p == 1 ? Wk : Wv)) + h * (E_ * DH_);
  int tid = threadIdx.x;
#pragma unroll
  for (int r = 0; r < 16; ++r) {
    int idx = r * 256 + tid;
    int el = idx >> 6, d = idx & 63;
    tile[el][d] = f2bf(src[(e0 + el) * DH_ + d]);
  }
  __syncthreads();
  u16* dst = wt + (p * HD_ + h * DH_) * E_;
#pragma unroll
  for (int r = 0; r < 16; ++r) {
    int idx = r * 256 + tid;
    int d = idx >> 6, el = idx & 63;
    dst[d * E_ + e0 + el] = tile[el][d];
  }
}

__global__ __launch_bounds__(256) void pack_wo_kernel(const float* __restrict__ Wo,
                                                      u16* __restrict__ wt) {
  __shared__ u16 tile[64][66];
  int c0 = blockIdx.y * 64, e0 = blockIdx.x * 64;
  int tid = threadIdx.x;
#pragma unroll
  for (int r = 0; r < 16; ++r) {
    int idx = r * 256 + tid;
    int cl = idx >> 6, el = idx & 63;
    tile[cl][el] = f2bf(Wo[(c0 + cl) * E_ + e0 + el]);
  }
  __syncthreads();
#pragma unroll
  for (int r = 0; r < 16; ++r) {
    int idx = r * 256 + tid;
    int er = idx >> 6, cl = idx & 63;
    wt[(e0 + er) * HD_ + c0 + cl] = tile[cl][er];
  }
}

__global__ __launch_bounds__(256) void pack_bias_kernel(
    const float* __restrict__ bq, const float* __restrict__ bk,
    const float* __restrict__ bv, float* __restrict__ bb) {
  int i = blockIdx.x * 256 + threadIdx.x;
  const float* s = (i < 1024 ? bq : (i < 2048 ? bk : bv));
  bb[i] = s[i & 1023];
}

// ---------------- GEMM: C[M][N] = A[M][K] * Bt[N][K]^T, K = 1024 ----------------
template <int MODE>
__global__ __launch_bounds__(256) void gemm_bt_kernel(
    const u16* __restrict__ A, const u16* __restrict__ Bt,
    const float* __restrict__ bias,
    u16* __restrict__ oQ, u16* __restrict__ oK, u16* __restrict__ oV,
    float* __restrict__ oF) {
  constexpr int K = 1024;
  __shared__ __align__(16) u16 As[128 * 32];
  __shared__ __align__(16) u16 Bs[128 * 32];
  const int tid = threadIdx.x;
  const int lane = tid & 63, wv = tid >> 6;
  const int wm = (wv >> 1) * 64, wn = (wv & 1) * 64;
  const int q4 = lane >> 4, lm = lane & 15;
  const int tileM = blockIdx.y * 128, tileN = blockIdx.x * 128;

  const int c0 = tid, c1 = tid + 256;
  const u16* gA0 = A + (tileM + (c0 >> 2)) * K + (((c0 & 3) ^ ((c0 >> 2) & 3)) * 8);
  const u16* gA1 = A + (tileM + (c1 >> 2)) * K + (((c1 & 3) ^ ((c1 >> 2) & 3)) * 8);
  const u16* gB0 = Bt + (tileN + (c0 >> 2)) * K + (((c0 & 3) ^ ((c0 >> 2) & 3)) * 8);
  const u16* gB1 = Bt + (tileN + (c1 >> 2)) * K + (((c1 & 3) ^ ((c1 >> 2) & 3)) * 8);
  u16* lA0 = As + c0 * 8; u16* lA1 = As + c1 * 8;
  u16* lB0 = Bs + c0 * 8; u16* lB1 = Bs + c1 * 8;

  f32x4 acc[4][4] = {};

  int aoff[4], boff[4];
#pragma unroll
  for (int i = 0; i < 4; ++i) {
    int ra = wm + i * 16 + lm;
    aoff[i] = ra * 32 + ((q4 ^ (ra & 3)) * 8);
    int rb = wn + i * 16 + lm;
    boff[i] = rb * 32 + ((q4 ^ (rb & 3)) * 8);
  }

  for (int k0 = 0; k0 < K; k0 += 32) {
    g2l16(gA0 + k0, lA0);
    g2l16(gA1 + k0, lA1);
    g2l16(gB0 + k0, lB0);
    g2l16(gB1 + k0, lB1);
    __syncthreads();
    bf16x8 af[4], bf[4];
#pragma unroll
    for (int i = 0; i < 4; ++i) af[i] = *(const bf16x8*)(As + aoff[i]);
#pragma unroll
    for (int j = 0; j < 4; ++j) bf[j] = *(const bf16x8*)(Bs + boff[j]);
#pragma unroll
    for (int i = 0; i < 4; ++i)
#pragma unroll
      for (int j = 0; j < 4; ++j)
        acc[i][j] = __builtin_amdgcn_mfma_f32_16x16x32_bf16(af[i], bf[j], acc[i][j], 0, 0, 0);
    __syncthreads();
  }

#pragma unroll
  for (int j = 0; j < 4; ++j) {
    int n = tileN + wn + j * 16 + lm;
    float bs = bias[n];
#pragma unroll
    for (int i = 0; i < 4; ++i) {
#pragma unroll
      for (int r = 0; r < 4; ++r) {
        int m = tileM + wm + i * 16 + q4 * 4 + r;
        float val = acc[i][j][r] + bs;
        if (MODE == 1) {
          oF[m * HD_ + n] = val;
        } else {
          int proj = n >> 10, cc = n & 1023;   // uniform per block
          if (proj == 0) {
            oQ[m * 1024 + cc] = f2bf(val * QSCALE);   // fold softmax scale+log2e into Q
          } else if (proj == 1) {
            oK[m * 1024 + cc] = f2bf(val);
          } else {
            int bb = m >> 11, ss = m & 2047, hh = cc >> 6, dd = cc & 63;
            oV[((bb * H_ + hh) * DH_ + dd) * S_ + ss] = f2bf(val);   // V^T [b,h,d,s]
          }
        }
      }
    }
  }
}

// ---------------- flash attention ----------------
// Block: 64 q-rows of one (b,h); wave wv owns q-rows [wv*16, wv*16+16), all keys.
// K/V double-buffered in LDS via global_load_lds (one barrier per tile).
// No-max exp2 softmax; S^T MFMA so P-writes are packed b64; li via ones-MFMA.
// All LDS offsets lane-constant; XOR swizzle keeps every access 2-way max (free).
__global__ __launch_bounds__(256, 4) void flash_kernel(
    const u16* __restrict__ Q, const u16* __restrict__ Kb,
    const u16* __restrict__ Vt, u16* __restrict__ Z) {
  __shared__ __align__(16) u16 Ks[2][64 * 64];   // [key][d] swizzled
  __shared__ __align__(16) u16 Vs[2][64 * 64];   // [d][key] swizzled
  __shared__ __align__(16) u16 Ps[4][16 * 64];   // per-wave P [q][key] swizzled
  const int tid = threadIdx.x, lane = tid & 63, wv = tid >> 6;
  const int q4 = lane >> 4, lm = lane & 15;

  const int bid = blockIdx.x;
  const int bh = bid >> 5, qt = bid & 31;        // 32 consecutive blocks share (b,h) K/V
  const int b = bh >> 4, h = bh & 15;

  const u16* qbase = Q + ((size_t)(b * S_ + qt * 64)) * HD_ + h * DH_;
  const u16* kbase = Kb + (size_t)b * S_ * HD_ + h * DH_;
  const u16* vbase = Vt + ((size_t)(b * H_ + h)) * DH_ * S_;
  u16* zbase = Z + ((size_t)(b * S_ + qt * 64)) * HD_ + h * DH_;

  // staging thread coords (row, swizzled source chunk), two rounds of 256 threads
  const int c0 = tid,       r0 = c0 >> 3, s0 = ((c0 & 7) ^ (r0 & 7)) * 8;
  const int c1 = tid + 256, r1 = c1 >> 3, s1 = ((c1 & 7) ^ (r1 & 7)) * 8;

  // persistent Q B-frags: B[k=d][col=q], q = wv*16+lm, d = dc*32 + q4*8 ..+7
  bf16x8 qf[2];
#pragma unroll
  for (int dc = 0; dc < 2; ++dc)
    qf[dc] = *(const bf16x8*)(qbase + (wv * 16 + lm) * HD_ + dc * 32 + q4 * 8);

  const bf16x8 ones = {(__bf16)1.f, (__bf16)1.f, (__bf16)1.f, (__bf16)1.f,
                       (__bf16)1.f, (__bf16)1.f, (__bf16)1.f, (__bf16)1.f};

  // lane-constant LDS offsets (u16 units)
  int koff[4][2], voff[2][4], pwoff[4], proff[2];
#pragma unroll
  for (int kb = 0; kb < 4; ++kb)
#pragma unroll
    for (int dc = 0; dc < 2; ++dc) {
      int row = kb * 16 + lm;
      koff[kb][dc] = row * 64 + (((dc * 4 + q4) ^ (row & 7)) * 8);
    }
#pragma unroll
  for (int ck = 0; ck < 2; ++ck)
#pragma unroll
    for (int db = 0; db < 4; ++db) {
      int row = db * 16 + lm;
      voff[ck][db] = row * 64 + (((ck * 4 + q4) ^ (row & 7)) * 8);
    }
#pragma unroll
  for (int kb = 0; kb < 4; ++kb) {
    int kc = kb * 2 + (q4 >> 1);
    pwoff[kb] = lm * 64 + ((kc ^ (lm & 7)) * 8) + (q4 & 1) * 4;
  }
#pragma unroll
  for (int ck = 0; ck < 2; ++ck)
    proff[ck] = lm * 64 + (((ck * 4 + q4) ^ (lm & 7)) * 8);

  f32x4 oacc[4] = {};
  f32x4 liacc = {};
  u16* Pw = Ps[wv];

  // stage tile 0 into buffer 0
  {
    const u16* kt = kbase;
    const u16* vt = vbase;
    g2l16(kt + r0 * HD_ + s0, Ks[0] + c0 * 8);
    g2l16(kt + r1 * HD_ + s1, Ks[0] + c1 * 8);
    g2l16(vt + r0 * S_ + s0, Vs[0] + c0 * 8);
    g2l16(vt + r1 * S_ + s1, Vs[0] + c1 * 8);
  }

  for (int t = 0; t < 32; ++t) {
    const int pb = t & 1;
    __syncthreads();                      // staging of tile t complete; tile t-1 reads done
    if (t < 31) {                         // prefetch tile t+1 into the other buffer
      const u16* kt = kbase + (size_t)(t + 1) * 64 * HD_;
      const u16* vt = vbase + (t + 1) * 64;
      g2l16(kt + r0 * HD_ + s0, Ks[1 - pb] + c0 * 8);
      g2l16(kt + r1 * HD_ + s1, Ks[1 - pb] + c1 * 8);
      g2l16(vt + r0 * S_ + s0, Vs[1 - pb] + c0 * 8);
      g2l16(vt + r1 * S_ + s1, Vs[1 - pb] + c1 * 8);
    }
    const u16* Kp = Ks[pb];
    const u16* Vp = Vs[pb];

    // ---- S^T = K·Q^T (rows=keys, cols=q), exp2, pack to wave-private P ----
#pragma unroll
    for (int kb = 0; kb < 4; ++kb) {
      bf16x8 k0 = *(const bf16x8*)(Kp + koff[kb][0]);
      bf16x8 k1 = *(const bf16x8*)(Kp + koff[kb][1]);
      f32x4 sc = {};
      sc = __builtin_amdgcn_mfma_f32_16x16x32_bf16(k0, qf[0], sc, 0, 0, 0);
      sc = __builtin_amdgcn_mfma_f32_16x16x32_bf16(k1, qf[1], sc, 0, 0, 0);
      f32x4 p;
#pragma unroll
      for (int r = 0; r < 4; ++r) p[r] = EXP2F(sc[r]);
      bf16x4 pbv = __builtin_convertvector(p, bf16x4);
      *(bf16x4*)(Pw + pwoff[kb]) = pbv;   // 4 consecutive keys, row q=lm
    }
    asm volatile("s_waitcnt lgkmcnt(0)" ::: "memory");  // wave-private P: no barrier

    // ---- O += P·V ; li += P·1 ----
#pragma unroll
    for (int ck = 0; ck < 2; ++ck) {
      bf16x8 pf = *(const bf16x8*)(Pw + proff[ck]);
      liacc = __builtin_amdgcn_mfma_f32_16x16x32_bf16(pf, ones, liacc, 0, 0, 0);
#pragma unroll
      for (int db = 0; db < 4; ++db) {
        bf16x8 vf = *(const bf16x8*)(Vp + voff[ck][db]);
        oacc[db] = __builtin_amdgcn_mfma_f32_16x16x32_bf16(pf, vf, oacc[db], 0, 0, 0);
      }
    }
  }

  // ---- normalize + store (wave owns its 16 q-rows; li is in-lane) ----
  float rin[4];
#pragma unroll
  for (int r = 0; r < 4; ++r) rin[r] = 1.f / liacc[r];
#pragma unroll
  for (int db = 0; db < 4; ++db)
#pragma unroll
    for (int r = 0; r < 4; ++r)
      zbase[(wv * 16 + q4 * 4 + r) * HD_ + db * 16 + lm] = f2bf(oacc[db][r] * rin[r]);
}

// ---------------- host ----------------
extern "C" void kernel_launch(void* const* d_in, const int* in_sizes, int n_in,
                              void* d_out, int out_size, void* d_ws, size_t ws_size,
                              hipStream_t stream) {
  const float* x  = (const float*)d_in[0];
  const float* Wq = (const float*)d_in[1];
  const float* bq = (const float*)d_in[2];
  const float* Wk = (const float*)d_in[3];
  const float* bk = (const float*)d_in[4];
  const float* Wv = (const float*)d_in[5];
  const float* bv = (const float*)d_in[6];
  const float* Wo = (const float*)d_in[7];
  const float* bo = (const float*)d_in[8];
  float* out = (float*)d_out;

  char* w = (char*)d_ws;
  u16*   xb    = (u16*)w;   w += (size_t)M_ * E_ * 2;
  u16*   wqkvT = (u16*)w;   w += (size_t)3 * HD_ * E_ * 2;
  u16*   woT   = (u16*)w;   w += (size_t)E_ * HD_ * 2;
  float* bqkv  = (float*)w; w += (size_t)3 * HD_ * 4;
  u16*   qB    = (u16*)w;   w += (size_t)M_ * HD_ * 2;
  u16*   kB    = (u16*)w;   w += (size_t)M_ * HD_ * 2;
  u16*   vT    = (u16*)w;   w += (size_t)M_ * HD_ * 2;
  u16*   zB    = (u16*)w;   w += (size_t)M_ * HD_ * 2;

  cvt_x_kernel<<<dim3(M_ * E_ / 4 / 256), 256, 0, stream>>>(x, xb);
  pack_wqkv_kernel<<<dim3(16, 16, 3), 256, 0, stream>>>(Wq, Wk, Wv, wqkvT);
  pack_wo_kernel<<<dim3(16, 16), 256, 0, stream>>>(Wo, woT);
  pack_bias_kernel<<<dim3(12), 256, 0, stream>>>(bq, bk, bv, bqkv);
  gemm_bt_kernel<0><<<dim3(24, 64), 256, 0, stream>>>(xb, wqkvT, bqkv, qB, kB, vT, nullptr);
  flash_kernel<<<dim3(2048), 256, 0, stream>>>(qB, kB, vT, zB);
  gemm_bt_kernel<1><<<dim3(8, 64), 256, 0, stream>>>(zB, woT, bo, nullptr, nullptr, nullptr, out);
}

// Round 4
// 317.136 us; speedup vs baseline: 1.6082x; 1.0216x over previous
//
#include <hip/hip_runtime.h>
#include <hip/hip_bf16.h>

#define B_  4
#define S_  2048
#define E_  1024
#define H_  16
#define DH_ 64
#define M_  (B_*S_)    // 8192 rows
#define HD_ (H_*DH_)   // 1024

typedef unsigned short u16;
typedef __attribute__((ext_vector_type(8))) __bf16 bf16x8;
typedef __attribute__((ext_vector_type(4))) __bf16 bf16x4;
typedef __attribute__((ext_vector_type(4))) float  f32x4;

#if __has_builtin(__builtin_amdgcn_exp2f)
#define EXP2F __builtin_amdgcn_exp2f
#else
#define EXP2F __builtin_exp2f
#endif

// softmax scale folded into Q at QKV epilogue: 1/sqrt(64) * log2(e)
#define QSCALE 0.18033688011112042f

// ---- async global->LDS, 16B per lane ----
__device__ __forceinline__ void g2l16(const void* g, void* l) {
  __builtin_amdgcn_global_load_lds(
      (const __attribute__((address_space(1))) void*)g,
      (__attribute__((address_space(3))) void*)l, 16, 0, 0);
}

// RNE float -> bf16 bits
__device__ __forceinline__ u16 f2bf(float f) {
  union { float f; unsigned u; } v; v.f = f;
  unsigned r = v.u + 0x7FFFu + ((v.u >> 16) & 1u);
  return (u16)(r >> 16);
}

// ---------------- conversion / packing kernels ----------------
__global__ __launch_bounds__(256) void cvt_x_kernel(const float* __restrict__ x,
                                                    u16* __restrict__ xb) {
  int i = blockIdx.x * 256 + threadIdx.x;
  float4 v = ((const float4*)x)[i];
  ushort4 o;
  o.x = f2bf(v.x); o.y = f2bf(v.y); o.z = f2bf(v.z); o.w = f2bf(v.w);
  ((ushort4*)xb)[i] = o;
}

__global__ __launch_bounds__(256) void pack_wqkv_kernel(
    const float* __restrict__ Wq, const float* __restrict__ Wk,
    const float* __restrict__ Wv, u16* __restrict__ wt) {
  __shared__ u16 tile[64][66];
  int p = blockIdx.z, h = blockIdx.y, e0 = blockIdx.x * 64;
  const float* src = (p == 0 ? Wq : (p == 1 ? Wk : Wv)) + h * (E_ * DH_);
  int tid = threadIdx.x;
#pragma unroll
  for (int r = 0; r < 16; ++r) {
    int idx = r * 256 + tid;
    int el = idx >> 6, d = idx & 63;
    tile[el][d] = f2bf(src[(e0 + el) * DH_ + d]);
  }
  __syncthreads();
  u16* dst = wt + (p * HD_ + h * DH_) * E_;
#pragma unroll
  for (int r = 0; r < 16; ++r) {
    int idx = r * 256 + tid;
    int d = idx >> 6, el = idx & 63;
    dst[d * E_ + e0 + el] = tile[el][d];
  }
}

__global__ __launch_bounds__(256) void pack_wo_kernel(const float* __restrict__ Wo,
                                                      u16* __restrict__ wt) {
  __shared__ u16 tile[64][66];
  int c0 = blockIdx.y * 64, e0 = blockIdx.x * 64;
  int tid = threadIdx.x;
#pragma unroll
  for (int r = 0; r < 16; ++r) {
    int idx = r * 256 + tid;
    int cl = idx >> 6, el = idx & 63;
    tile[cl][el] = f2bf(Wo[(c0 + cl) * E_ + e0 + el]);
  }
  __syncthreads();
#pragma unroll
  for (int r = 0; r < 16; ++r) {
    int idx = r * 256 + tid;
    int er = idx >> 6, cl = idx & 63;
    wt[(e0 + er) * HD_ + c0 + cl] = tile[cl][er];
  }
}

__global__ __launch_bounds__(256) void pack_bias_kernel(
    const float* __restrict__ bq, const float* __restrict__ bk,
    const float* __restrict__ bv, float* __restrict__ bb) {
  int i = blockIdx.x * 256 + threadIdx.x;
  const float* s = (i < 1024 ? bq : (i < 2048 ? bk : bv));
  bb[i] = s[i & 1023];
}

// ---------------- GEMM: C[M][N] = A[M][K] * Bt[N][K]^T, K = 1024 ----------------
template <int MODE>
__global__ __launch_bounds__(256) void gemm_bt_kernel(
    const u16* __restrict__ A, const u16* __restrict__ Bt,
    const float* __restrict__ bias,
    u16* __restrict__ oQ, u16* __restrict__ oK, u16* __restrict__ oV,
    float* __restrict__ oF) {
  constexpr int K = 1024;
  __shared__ __align__(16) u16 As[128 * 32];
  __shared__ __align__(16) u16 Bs[128 * 32];
  const int tid = threadIdx.x;
  const int lane = tid & 63, wv = tid >> 6;
  const int wm = (wv >> 1) * 64, wn = (wv & 1) * 64;
  const int q4 = lane >> 4, lm = lane & 15;
  const int tileM = blockIdx.y * 128, tileN = blockIdx.x * 128;

  const int c0 = tid, c1 = tid + 256;
  const u16* gA0 = A + (tileM + (c0 >> 2)) * K + (((c0 & 3) ^ ((c0 >> 2) & 3)) * 8);
  const u16* gA1 = A + (tileM + (c1 >> 2)) * K + (((c1 & 3) ^ ((c1 >> 2) & 3)) * 8);
  const u16* gB0 = Bt + (tileN + (c0 >> 2)) * K + (((c0 & 3) ^ ((c0 >> 2) & 3)) * 8);
  const u16* gB1 = Bt + (tileN + (c1 >> 2)) * K + (((c1 & 3) ^ ((c1 >> 2) & 3)) * 8);
  u16* lA0 = As + c0 * 8; u16* lA1 = As + c1 * 8;
  u16* lB0 = Bs + c0 * 8; u16* lB1 = Bs + c1 * 8;

  f32x4 acc[4][4] = {};

  int aoff[4], boff[4];
#pragma unroll
  for (int i = 0; i < 4; ++i) {
    int ra = wm + i * 16 + lm;
    aoff[i] = ra * 32 + ((q4 ^ (ra & 3)) * 8);
    int rb = wn + i * 16 + lm;
    boff[i] = rb * 32 + ((q4 ^ (rb & 3)) * 8);
  }

  for (int k0 = 0; k0 < K; k0 += 32) {
    g2l16(gA0 + k0, lA0);
    g2l16(gA1 + k0, lA1);
    g2l16(gB0 + k0, lB0);
    g2l16(gB1 + k0, lB1);
    __syncthreads();
    bf16x8 af[4], bf[4];
#pragma unroll
    for (int i = 0; i < 4; ++i) af[i] = *(const bf16x8*)(As + aoff[i]);
#pragma unroll
    for (int j = 0; j < 4; ++j) bf[j] = *(const bf16x8*)(Bs + boff[j]);
#pragma unroll
    for (int i = 0; i < 4; ++i)
#pragma unroll
      for (int j = 0; j < 4; ++j)
        acc[i][j] = __builtin_amdgcn_mfma_f32_16x16x32_bf16(af[i], bf[j], acc[i][j], 0, 0, 0);
    __syncthreads();
  }

#pragma unroll
  for (int j = 0; j < 4; ++j) {
    int n = tileN + wn + j * 16 + lm;
    float bs = bias[n];
#pragma unroll
    for (int i = 0; i < 4; ++i) {
#pragma unroll
      for (int r = 0; r < 4; ++r) {
        int m = tileM + wm + i * 16 + q4 * 4 + r;
        float val = acc[i][j][r] + bs;
        if (MODE == 1) {
          oF[m * HD_ + n] = val;
        } else {
          int proj = n >> 10, cc = n & 1023;   // uniform per block
          if (proj == 0) {
            oQ[m * 1024 + cc] = f2bf(val * QSCALE);   // fold softmax scale+log2e into Q
          } else if (proj == 1) {
            oK[m * 1024 + cc] = f2bf(val);
          } else {
            int bb = m >> 11, ss = m & 2047, hh = cc >> 6, dd = cc & 63;
            oV[((bb * H_ + hh) * DH_ + dd) * S_ + ss] = f2bf(val);   // V^T [b,h,d,s]
          }
        }
      }
    }
  }
}

// ---------------- flash attention ----------------
// Block: 128 q-rows of one (b,h); wave wv owns q-rows [wv*32, wv*32+32), all keys.
// K/V double-buffered in LDS via global_load_lds (one barrier per tile).
// 32 q-rows/wave doubles MFMA per LDS byte vs 16 (LDS pipe is the bottleneck).
// No-max exp2 softmax; S^T MFMA so P-writes are packed b64; li via ones-MFMA.
__global__ __launch_bounds__(256, 3) void flash_kernel(
    const u16* __restrict__ Q, const u16* __restrict__ Kb,
    const u16* __restrict__ Vt, u16* __restrict__ Z) {
  __shared__ __align__(16) u16 Ks[2][64 * 64];   // [key][d] swizzled
  __shared__ __align__(16) u16 Vs[2][64 * 64];   // [d][key] swizzled
  __shared__ __align__(16) u16 Ps[4][32 * 64];   // per-wave P [q(32)][key] swizzled
  const int tid = threadIdx.x, lane = tid & 63, wv = tid >> 6;
  const int q4 = lane >> 4, lm = lane & 15;

  const int bid = blockIdx.x;
  const int bh = bid >> 4, qt = bid & 15;        // 16 consecutive blocks share (b,h) K/V
  const int b = bh >> 4, h = bh & 15;

  const u16* qbase = Q + ((size_t)(b * S_ + qt * 128)) * HD_ + h * DH_;
  const u16* kbase = Kb + (size_t)b * S_ * HD_ + h * DH_;
  const u16* vbase = Vt + ((size_t)(b * H_ + h)) * DH_ * S_;
  u16* zbase = Z + ((size_t)(b * S_ + qt * 128)) * HD_ + h * DH_;

  // staging thread coords (row, swizzled source chunk), two rounds of 256 threads
  const int c0 = tid,       r0 = c0 >> 3, s0 = ((c0 & 7) ^ (r0 & 7)) * 8;
  const int c1 = tid + 256, r1 = c1 >> 3, s1 = ((c1 & 7) ^ (r1 & 7)) * 8;

  // persistent Q B-frags: q-row = wv*32 + qs*16 + lm, d = dc*32 + q4*8 ..+7
  bf16x8 qf[2][2];
#pragma unroll
  for (int qs = 0; qs < 2; ++qs)
#pragma unroll
    for (int dc = 0; dc < 2; ++dc)
      qf[qs][dc] = *(const bf16x8*)(qbase + (wv * 32 + qs * 16 + lm) * HD_ + dc * 32 + q4 * 8);

  const bf16x8 ones = {(__bf16)1.f, (__bf16)1.f, (__bf16)1.f, (__bf16)1.f,
                       (__bf16)1.f, (__bf16)1.f, (__bf16)1.f, (__bf16)1.f};

  // lane-constant LDS offsets (u16 units)
  int koff[4][2], voff[2][4], pwoff[4], proff[2];
#pragma unroll
  for (int kb = 0; kb < 4; ++kb)
#pragma unroll
    for (int dc = 0; dc < 2; ++dc) {
      int row = kb * 16 + lm;
      koff[kb][dc] = row * 64 + (((dc * 4 + q4) ^ (row & 7)) * 8);
    }
#pragma unroll
  for (int ck = 0; ck < 2; ++ck)
#pragma unroll
    for (int db = 0; db < 4; ++db) {
      int row = db * 16 + lm;
      voff[ck][db] = row * 64 + (((ck * 4 + q4) ^ (row & 7)) * 8);
    }
  // P write: row_p = qs*16 + lm (qs handled by +16*64 offset), 4 keys at kb*16+q4*4
#pragma unroll
  for (int kb = 0; kb < 4; ++kb) {
    int kc = kb * 2 + (q4 >> 1);
    pwoff[kb] = lm * 64 + ((kc ^ (lm & 7)) * 8) + (q4 & 1) * 4;
  }
#pragma unroll
  for (int ck = 0; ck < 2; ++ck)
    proff[ck] = lm * 64 + (((ck * 4 + q4) ^ (lm & 7)) * 8);

  f32x4 oacc[2][4] = {};
  f32x4 liacc[2] = {};
  u16* Pw = Ps[wv];

  // stage tile 0 into buffer 0
  {
    g2l16(kbase + r0 * HD_ + s0, Ks[0] + c0 * 8);
    g2l16(kbase + r1 * HD_ + s1, Ks[0] + c1 * 8);
    g2l16(vbase + r0 * S_ + s0, Vs[0] + c0 * 8);
    g2l16(vbase + r1 * S_ + s1, Vs[0] + c1 * 8);
  }

  for (int t = 0; t < 32; ++t) {
    const int pb = t & 1;
    __syncthreads();                      // staging of tile t complete
    if (t < 31) {                         // prefetch tile t+1 into the other buffer
      const u16* kt = kbase + (size_t)(t + 1) * 64 * HD_;
      const u16* vt = vbase + (t + 1) * 64;
      g2l16(kt + r0 * HD_ + s0, Ks[1 - pb] + c0 * 8);
      g2l16(kt + r1 * HD_ + s1, Ks[1 - pb] + c1 * 8);
      g2l16(vt + r0 * S_ + s0, Vs[1 - pb] + c0 * 8);
      g2l16(vt + r1 * S_ + s1, Vs[1 - pb] + c1 * 8);
    }
    const u16* Kp = Ks[pb];
    const u16* Vp = Vs[pb];

    // ---- S^T = K·Q^T (rows=keys, cols=q), exp2, pack to wave-private P ----
#pragma unroll
    for (int kb = 0; kb < 4; ++kb) {
      bf16x8 k0 = *(const bf16x8*)(Kp + koff[kb][0]);
      bf16x8 k1 = *(const bf16x8*)(Kp + koff[kb][1]);
#pragma unroll
      for (int qs = 0; qs < 2; ++qs) {
        f32x4 sc = {};
        sc = __builtin_amdgcn_mfma_f32_16x16x32_bf16(k0, qf[qs][0], sc, 0, 0, 0);
        sc = __builtin_amdgcn_mfma_f32_16x16x32_bf16(k1, qf[qs][1], sc, 0, 0, 0);
        f32x4 p;
#pragma unroll
        for (int r = 0; r < 4; ++r) p[r] = EXP2F(sc[r]);
        bf16x4 pbv = __builtin_convertvector(p, bf16x4);
        *(bf16x4*)(Pw + qs * (16 * 64) + pwoff[kb]) = pbv;   // 4 consecutive keys
      }
    }
    asm volatile("s_waitcnt lgkmcnt(0)" ::: "memory");  // wave-private P: no barrier

    // ---- O += P·V ; li += P·1 ----
#pragma unroll
    for (int ck = 0; ck < 2; ++ck) {
      bf16x8 pf0 = *(const bf16x8*)(Pw + proff[ck]);
      bf16x8 pf1 = *(const bf16x8*)(Pw + 16 * 64 + proff[ck]);
      liacc[0] = __builtin_amdgcn_mfma_f32_16x16x32_bf16(pf0, ones, liacc[0], 0, 0, 0);
      liacc[1] = __builtin_amdgcn_mfma_f32_16x16x32_bf16(pf1, ones, liacc[1], 0, 0, 0);
#pragma unroll
      for (int db = 0; db < 4; ++db) {
        bf16x8 vf = *(const bf16x8*)(Vp + voff[ck][db]);
        oacc[0][db] = __builtin_amdgcn_mfma_f32_16x16x32_bf16(pf0, vf, oacc[0][db], 0, 0, 0);
        oacc[1][db] = __builtin_amdgcn_mfma_f32_16x16x32_bf16(pf1, vf, oacc[1][db], 0, 0, 0);
      }
    }
  }

  // ---- normalize + store (wave owns its 32 q-rows; li is in-lane) ----
#pragma unroll
  for (int qs = 0; qs < 2; ++qs) {
    float rin[4];
#pragma unroll
    for (int r = 0; r < 4; ++r) rin[r] = 1.f / liacc[qs][r];
#pragma unroll
    for (int db = 0; db < 4; ++db)
#pragma unroll
      for (int r = 0; r < 4; ++r)
        zbase[(wv * 32 + qs * 16 + q4 * 4 + r) * HD_ + db * 16 + lm] =
            f2bf(oacc[qs][db][r] * rin[r]);
  }
}

// ---------------- host ----------------
extern "C" void kernel_launch(void* const* d_in, const int* in_sizes, int n_in,
                              void* d_out, int out_size, void* d_ws, size_t ws_size,
                              hipStream_t stream) {
  const float* x  = (const float*)d_in[0];
  const float* Wq = (const float*)d_in[1];
  const float* bq = (const float*)d_in[2];
  const float* Wk = (const float*)d_in[3];
  const float* bk = (const float*)d_in[4];
  const float* Wv = (const float*)d_in[5];
  const float* bv = (const float*)d_in[6];
  const float* Wo = (const float*)d_in[7];
  const float* bo = (const float*)d_in[8];
  float* out = (float*)d_out;

  char* w = (char*)d_ws;
  u16*   xb    = (u16*)w;   w += (size_t)M_ * E_ * 2;
  u16*   wqkvT = (u16*)w;   w += (size_t)3 * HD_ * E_ * 2;
  u16*   woT   = (u16*)w;   w += (size_t)E_ * HD_ * 2;
  float* bqkv  = (float*)w; w += (size_t)3 * HD_ * 4;
  u16*   qB    = (u16*)w;   w += (size_t)M_ * HD_ * 2;
  u16*   kB    = (u16*)w;   w += (size_t)M_ * HD_ * 2;
  u16*   vT    = (u16*)w;   w += (size_t)M_ * HD_ * 2;
  u16*   zB    = (u16*)w;   w += (size_t)M_ * HD_ * 2;

  cvt_x_kernel<<<dim3(M_ * E_ / 4 / 256), 256, 0, stream>>>(x, xb);
  pack_wqkv_kernel<<<dim3(16, 16, 3), 256, 0, stream>>>(Wq, Wk, Wv, wqkvT);
  pack_wo_kernel<<<dim3(16, 16), 256, 0, stream>>>(Wo, woT);
  pack_bias_kernel<<<dim3(12), 256, 0, stream>>>(bq, bk, bv, bqkv);
  gemm_bt_kernel<0><<<dim3(24, 64), 256, 0, stream>>>(xb, wqkvT, bqkv, qB, kB, vT, nullptr);
  flash_kernel<<<dim3(1024), 256, 0, stream>>>(qB, kB, vT, zB);
  gemm_bt_kernel<1><<<dim3(8, 64), 256, 0, stream>>>(zB, woT, bo, nullptr, nullptr, nullptr, out);
}

// Round 5
// 290.464 us; speedup vs baseline: 1.7558x; 1.0918x over previous
//
#include <hip/hip_runtime.h>
#include <hip/hip_bf16.h>

#define B_  4
#define S_  2048
#define E_  1024
#define H_  16
#define DH_ 64
#define M_  (B_*S_)    // 8192 rows
#define HD_ (H_*DH_)   // 1024

typedef unsigned short u16;
typedef __attribute__((ext_vector_type(8))) __bf16 bf16x8;
typedef __attribute__((ext_vector_type(4))) __bf16 bf16x4;
typedef __attribute__((ext_vector_type(4))) float  f32x4;

#if __has_builtin(__builtin_amdgcn_exp2f)
#define EXP2F __builtin_amdgcn_exp2f
#else
#define EXP2F __builtin_exp2f
#endif

// softmax scale folded into Q at QKV epilogue: 1/sqrt(64) * log2(e)
#define QSCALE 0.18033688011112042f

// ---- async global->LDS, 16B per lane ----
__device__ __forceinline__ void g2l16(const void* g, void* l) {
  __builtin_amdgcn_global_load_lds(
      (const __attribute__((address_space(1))) void*)g,
      (__attribute__((address_space(3))) void*)l, 16, 0, 0);
}

// RNE float -> bf16 bits
__device__ __forceinline__ u16 f2bf(float f) {
  union { float f; unsigned u; } v; v.f = f;
  unsigned r = v.u + 0x7FFFu + ((v.u >> 16) & 1u);
  return (u16)(r >> 16);
}

// ---------------- conversion / packing kernels ----------------
__global__ __launch_bounds__(256) void cvt_x_kernel(const float* __restrict__ x,
                                                    u16* __restrict__ xb) {
  int i = blockIdx.x * 256 + threadIdx.x;
  float4 v = ((const float4*)x)[i];
  ushort4 o;
  o.x = f2bf(v.x); o.y = f2bf(v.y); o.z = f2bf(v.z); o.w = f2bf(v.w);
  ((ushort4*)xb)[i] = o;
}

__global__ __launch_bounds__(256) void pack_wqkv_kernel(
    const float* __restrict__ Wq, const float* __restrict__ Wk,
    const float* __restrict__ Wv, u16* __restrict__ wt) {
  __shared__ u16 tile[64][66];
  int p = blockIdx.z, h = blockIdx.y, e0 = blockIdx.x * 64;
  const float* src = (p == 0 ? Wq : (p == 1 ? Wk : Wv)) + h * (E_ * DH_);
  int tid = threadIdx.x;
#pragma unroll
  for (int r = 0; r < 16; ++r) {
    int idx = r * 256 + tid;
    int el = idx >> 6, d = idx & 63;
    tile[el][d] = f2bf(src[(e0 + el) * DH_ + d]);
  }
  __syncthreads();
  u16* dst = wt + (p * HD_ + h * DH_) * E_;
#pragma unroll
  for (int r = 0; r < 16; ++r) {
    int idx = r * 256 + tid;
    int d = idx >> 6, el = idx & 63;
    dst[d * E_ + e0 + el] = tile[el][d];
  }
}

__global__ __launch_bounds__(256) void pack_wo_kernel(const float* __restrict__ Wo,
                                                      u16* __restrict__ wt) {
  __shared__ u16 tile[64][66];
  int c0 = blockIdx.y * 64, e0 = blockIdx.x * 64;
  int tid = threadIdx.x;
#pragma unroll
  for (int r = 0; r < 16; ++r) {
    int idx = r * 256 + tid;
    int cl = idx >> 6, el = idx & 63;
    tile[cl][el] = f2bf(Wo[(c0 + cl) * E_ + e0 + el]);
  }
  __syncthreads();
#pragma unroll
  for (int r = 0; r < 16; ++r) {
    int idx = r * 256 + tid;
    int er = idx >> 6, cl = idx & 63;
    wt[(e0 + er) * HD_ + c0 + cl] = tile[cl][er];
  }
}

__global__ __launch_bounds__(256) void pack_bias_kernel(
    const float* __restrict__ bq, const float* __restrict__ bk,
    const float* __restrict__ bv, float* __restrict__ bb) {
  int i = blockIdx.x * 256 + threadIdx.x;
  const float* s = (i < 1024 ? bq : (i < 2048 ? bk : bv));
  bb[i] = s[i & 1023];
}

// ---- V transpose: [b,s,h,d] -> [b,h,d,s] (all stores/loads coalesced 16B) ----
__global__ __launch_bounds__(256) void transpose_v_kernel(
    const u16* __restrict__ vin, u16* __restrict__ vout) {
  __shared__ u16 t[64][72];
  const int tid = threadIdx.x;
  const int bh = blockIdx.y, st = blockIdx.x * 64;
  const u16* src = vin + ((size_t)((bh >> 4) * S_ + st)) * HD_ + (bh & 15) * 64;
#pragma unroll
  for (int rr = 0; rr < 2; ++rr) {
    int idx = rr * 256 + tid;
    int s = idx >> 3, ch = idx & 7;
    *(uint4*)&t[s][ch * 8] = *(const uint4*)(src + s * HD_ + ch * 8);
  }
  __syncthreads();
  u16* dst = vout + ((size_t)bh) * DH_ * S_ + st;
#pragma unroll
  for (int rr = 0; rr < 2; ++rr) {
    int idx = rr * 256 + tid;
    int d = idx >> 3, sc = (idx & 7) * 8;
    ushort4 o0, o1;
    o0.x = t[sc + 0][d]; o0.y = t[sc + 1][d]; o0.z = t[sc + 2][d]; o0.w = t[sc + 3][d];
    o1.x = t[sc + 4][d]; o1.y = t[sc + 5][d]; o1.z = t[sc + 6][d]; o1.w = t[sc + 7][d];
    *(ushort4*)(dst + (size_t)d * S_ + sc) = o0;
    *(ushort4*)(dst + (size_t)d * S_ + sc + 4) = o1;
  }
}

// ---------------- GEMM: C[M][N] = A[M][K] * Bt[N][K]^T, K = 1024 ----------------
// MODE 0: QKV epilogue — bias + bf16 store, all three projections coalesced
//         [m][cc] (V transposed later by transpose_v_kernel).
// MODE 1: out-proj epilogue (bias + fp32 store)
template <int MODE>
__global__ __launch_bounds__(256) void gemm_bt_kernel(
    const u16* __restrict__ A, const u16* __restrict__ Bt,
    const float* __restrict__ bias,
    u16* __restrict__ oQ, u16* __restrict__ oK, u16* __restrict__ oV,
    float* __restrict__ oF) {
  constexpr int K = 1024;
  __shared__ __align__(16) u16 As[128 * 32];
  __shared__ __align__(16) u16 Bs[128 * 32];
  const int tid = threadIdx.x;
  const int lane = tid & 63, wv = tid >> 6;
  const int wm = (wv >> 1) * 64, wn = (wv & 1) * 64;
  const int q4 = lane >> 4, lm = lane & 15;
  const int tileM = blockIdx.y * 128, tileN = blockIdx.x * 128;

  const int c0 = tid, c1 = tid + 256;
  const u16* gA0 = A + (tileM + (c0 >> 2)) * K + (((c0 & 3) ^ ((c0 >> 2) & 3)) * 8);
  const u16* gA1 = A + (tileM + (c1 >> 2)) * K + (((c1 & 3) ^ ((c1 >> 2) & 3)) * 8);
  const u16* gB0 = Bt + (tileN + (c0 >> 2)) * K + (((c0 & 3) ^ ((c0 >> 2) & 3)) * 8);
  const u16* gB1 = Bt + (tileN + (c1 >> 2)) * K + (((c1 & 3) ^ ((c1 >> 2) & 3)) * 8);
  u16* lA0 = As + c0 * 8; u16* lA1 = As + c1 * 8;
  u16* lB0 = Bs + c0 * 8; u16* lB1 = Bs + c1 * 8;

  f32x4 acc[4][4] = {};

  int aoff[4], boff[4];
#pragma unroll
  for (int i = 0; i < 4; ++i) {
    int ra = wm + i * 16 + lm;
    aoff[i] = ra * 32 + ((q4 ^ (ra & 3)) * 8);
    int rb = wn + i * 16 + lm;
    boff[i] = rb * 32 + ((q4 ^ (rb & 3)) * 8);
  }

  for (int k0 = 0; k0 < K; k0 += 32) {
    g2l16(gA0 + k0, lA0);
    g2l16(gA1 + k0, lA1);
    g2l16(gB0 + k0, lB0);
    g2l16(gB1 + k0, lB1);
    __syncthreads();
    bf16x8 af[4], bf[4];
#pragma unroll
    for (int i = 0; i < 4; ++i) af[i] = *(const bf16x8*)(As + aoff[i]);
#pragma unroll
    for (int j = 0; j < 4; ++j) bf[j] = *(const bf16x8*)(Bs + boff[j]);
#pragma unroll
    for (int i = 0; i < 4; ++i)
#pragma unroll
      for (int j = 0; j < 4; ++j)
        acc[i][j] = __builtin_amdgcn_mfma_f32_16x16x32_bf16(af[i], bf[j], acc[i][j], 0, 0, 0);
    __syncthreads();
  }

#pragma unroll
  for (int j = 0; j < 4; ++j) {
    int n = tileN + wn + j * 16 + lm;
    float bs = bias[n];
#pragma unroll
    for (int i = 0; i < 4; ++i) {
#pragma unroll
      for (int r = 0; r < 4; ++r) {
        int m = tileM + wm + i * 16 + q4 * 4 + r;
        float val = acc[i][j][r] + bs;
        if (MODE == 1) {
          oF[m * HD_ + n] = val;
        } else {
          int proj = n >> 10, cc = n & 1023;   // proj uniform per block
          u16* optr = (proj == 0 ? oQ : (proj == 1 ? oK : oV));
          float scl = (proj == 0 ? QSCALE : 1.0f);
          optr[m * 1024 + cc] = f2bf(val * scl);
        }
      }
    }
  }
}

// ---------------- flash attention ----------------
// Block: 256 q-rows of one (b,h); wave wv owns q-rows [wv*64, wv*64+64), all keys.
// K/V double-buffered in LDS via global_load_lds (one barrier per tile).
// 64 q-rows/wave: 72 MFMA per 24 ds_read_b128 per tile (LDS pipe was the limit).
// No-max exp2 softmax; S^T MFMA so P-writes are packed b64; li via ones-MFMA.
__global__ __launch_bounds__(256, 2) void flash_kernel(
    const u16* __restrict__ Q, const u16* __restrict__ Kb,
    const u16* __restrict__ Vt, u16* __restrict__ Z) {
  __shared__ __align__(16) u16 Ks[2][64 * 64];   // [key][d] swizzled
  __shared__ __align__(16) u16 Vs[2][64 * 64];   // [d][key] swizzled
  __shared__ __align__(16) u16 Ps[4][64 * 64];   // per-wave P [q(64)][key] swizzled
  const int tid = threadIdx.x, lane = tid & 63, wv = tid >> 6;
  const int q4 = lane >> 4, lm = lane & 15;

  const int bid = blockIdx.x;
  const int bh = bid >> 3, qt = bid & 7;         // 8 consecutive blocks share (b,h) K/V
  const int b = bh >> 4, h = bh & 15;

  const u16* qbase = Q + ((size_t)(b * S_ + qt * 256)) * HD_ + h * DH_;
  const u16* kbase = Kb + (size_t)b * S_ * HD_ + h * DH_;
  const u16* vbase = Vt + ((size_t)(b * H_ + h)) * DH_ * S_;
  u16* zbase = Z + ((size_t)(b * S_ + qt * 256)) * HD_ + h * DH_;

  // staging thread coords (row, swizzled source chunk), two rounds of 256 threads
  const int c0 = tid,       r0 = c0 >> 3, s0 = ((c0 & 7) ^ (r0 & 7)) * 8;
  const int c1 = tid + 256, r1 = c1 >> 3, s1 = ((c1 & 7) ^ (r1 & 7)) * 8;

  // persistent Q B-frags: q-row = wv*64 + qs*16 + lm, d = dc*32 + q4*8 ..+7
  bf16x8 qf[4][2];
#pragma unroll
  for (int qs = 0; qs < 4; ++qs)
#pragma unroll
    for (int dc = 0; dc < 2; ++dc)
      qf[qs][dc] = *(const bf16x8*)(qbase + (wv * 64 + qs * 16 + lm) * HD_ + dc * 32 + q4 * 8);

  const bf16x8 ones = {(__bf16)1.f, (__bf16)1.f, (__bf16)1.f, (__bf16)1.f,
                       (__bf16)1.f, (__bf16)1.f, (__bf16)1.f, (__bf16)1.f};

  // lane-constant LDS offsets (u16 units)
  int koff[4][2], voff[2][4], pwoff[4], proff[2];
#pragma unroll
  for (int kb = 0; kb < 4; ++kb)
#pragma unroll
    for (int dc = 0; dc < 2; ++dc) {
      int row = kb * 16 + lm;
      koff[kb][dc] = row * 64 + (((dc * 4 + q4) ^ (row & 7)) * 8);
    }
#pragma unroll
  for (int ck = 0; ck < 2; ++ck)
#pragma unroll
    for (int db = 0; db < 4; ++db) {
      int row = db * 16 + lm;
      voff[ck][db] = row * 64 + (((ck * 4 + q4) ^ (row & 7)) * 8);
    }
  // P write: row = qs*16 + lm (qs via +16*64), 4 keys at kb*16 + q4*4
#pragma unroll
  for (int kb = 0; kb < 4; ++kb) {
    int kc = kb * 2 + (q4 >> 1);
    pwoff[kb] = lm * 64 + ((kc ^ (lm & 7)) * 8) + (q4 & 1) * 4;
  }
#pragma unroll
  for (int ck = 0; ck < 2; ++ck)
    proff[ck] = lm * 64 + (((ck * 4 + q4) ^ (lm & 7)) * 8);

  f32x4 oacc[4][4] = {};
  f32x4 liacc[4] = {};
  u16* Pw = Ps[wv];

  // stage tile 0 into buffer 0
  {
    g2l16(kbase + r0 * HD_ + s0, Ks[0] + c0 * 8);
    g2l16(kbase + r1 * HD_ + s1, Ks[0] + c1 * 8);
    g2l16(vbase + r0 * S_ + s0, Vs[0] + c0 * 8);
    g2l16(vbase + r1 * S_ + s1, Vs[0] + c1 * 8);
  }

  for (int t = 0; t < 32; ++t) {
    const int pb = t & 1;
    __syncthreads();                      // staging of tile t complete
    if (t < 31) {                         // prefetch tile t+1 into the other buffer
      const u16* kt = kbase + (size_t)(t + 1) * 64 * HD_;
      const u16* vt = vbase + (t + 1) * 64;
      g2l16(kt + r0 * HD_ + s0, Ks[1 - pb] + c0 * 8);
      g2l16(kt + r1 * HD_ + s1, Ks[1 - pb] + c1 * 8);
      g2l16(vt + r0 * S_ + s0, Vs[1 - pb] + c0 * 8);
      g2l16(vt + r1 * S_ + s1, Vs[1 - pb] + c1 * 8);
    }
    const u16* Kp = Ks[pb];
    const u16* Vp = Vs[pb];

    // ---- S^T = K·Q^T (rows=keys, cols=q), exp2, pack to wave-private P ----
#pragma unroll
    for (int kb = 0; kb < 4; ++kb) {
      bf16x8 k0 = *(const bf16x8*)(Kp + koff[kb][0]);
      bf16x8 k1 = *(const bf16x8*)(Kp + koff[kb][1]);
#pragma unroll
      for (int qs = 0; qs < 4; ++qs) {
        f32x4 sc = {};
        sc = __builtin_amdgcn_mfma_f32_16x16x32_bf16(k0, qf[qs][0], sc, 0, 0, 0);
        sc = __builtin_amdgcn_mfma_f32_16x16x32_bf16(k1, qf[qs][1], sc, 0, 0, 0);
        f32x4 p;
#pragma unroll
        for (int r = 0; r < 4; ++r) p[r] = EXP2F(sc[r]);
        bf16x4 pbv = __builtin_convertvector(p, bf16x4);
        *(bf16x4*)(Pw + qs * (16 * 64) + pwoff[kb]) = pbv;   // 4 consecutive keys
      }
    }
    asm volatile("s_waitcnt lgkmcnt(0)" ::: "memory");  // wave-private P: no barrier

    // ---- O += P·V ; li += P·1 ----
#pragma unroll
    for (int ck = 0; ck < 2; ++ck) {
      bf16x8 pf[4];
#pragma unroll
      for (int qs = 0; qs < 4; ++qs)
        pf[qs] = *(const bf16x8*)(Pw + qs * (16 * 64) + proff[ck]);
#pragma unroll
      for (int qs = 0; qs < 4; ++qs)
        liacc[qs] = __builtin_amdgcn_mfma_f32_16x16x32_bf16(pf[qs], ones, liacc[qs], 0, 0, 0);
#pragma unroll
      for (int db = 0; db < 4; ++db) {
        bf16x8 vf = *(const bf16x8*)(Vp + voff[ck][db]);
#pragma unroll
        for (int qs = 0; qs < 4; ++qs)
          oacc[qs][db] = __builtin_amdgcn_mfma_f32_16x16x32_bf16(pf[qs], vf, oacc[qs][db], 0, 0, 0);
      }
    }
  }

  // ---- normalize + store (wave owns its 64 q-rows; li is in-lane) ----
#pragma unroll
  for (int qs = 0; qs < 4; ++qs) {
    float rin[4];
#pragma unroll
    for (int r = 0; r < 4; ++r) rin[r] = 1.f / liacc[qs][r];
#pragma unroll
    for (int db = 0; db < 4; ++db)
#pragma unroll
      for (int r = 0; r < 4; ++r)
        zbase[(wv * 64 + qs * 16 + q4 * 4 + r) * HD_ + db * 16 + lm] =
            f2bf(oacc[qs][db][r] * rin[r]);
  }
}

// ---------------- host ----------------
extern "C" void kernel_launch(void* const* d_in, const int* in_sizes, int n_in,
                              void* d_out, int out_size, void* d_ws, size_t ws_size,
                              hipStream_t stream) {
  const float* x  = (const float*)d_in[0];
  const float* Wq = (const float*)d_in[1];
  const float* bq = (const float*)d_in[2];
  const float* Wk = (const float*)d_in[3];
  const float* bk = (const float*)d_in[4];
  const float* Wv = (const float*)d_in[5];
  const float* bv = (const float*)d_in[6];
  const float* Wo = (const float*)d_in[7];
  const float* bo = (const float*)d_in[8];
  float* out = (float*)d_out;

  char* w = (char*)d_ws;
  u16*   xb    = (u16*)w;   w += (size_t)M_ * E_ * 2;
  u16*   wqkvT = (u16*)w;   w += (size_t)3 * HD_ * E_ * 2;
  u16*   woT   = (u16*)w;   w += (size_t)E_ * HD_ * 2;
  float* bqkv  = (float*)w; w += (size_t)3 * HD_ * 4;
  u16*   qB    = (u16*)w;   w += (size_t)M_ * HD_ * 2;
  u16*   kB    = (u16*)w;   w += (size_t)M_ * HD_ * 2;
  u16*   vT    = (u16*)w;   w += (size_t)M_ * HD_ * 2;
  u16*   zB    = (u16*)w;   w += (size_t)M_ * HD_ * 2;
  // vB ([b,s,h,d] pre-transpose V) aliases zB: consumed by transpose_v before
  // flash writes zB.
  u16*   vB    = zB;

  cvt_x_kernel<<<dim3(M_ * E_ / 4 / 256), 256, 0, stream>>>(x, xb);
  pack_wqkv_kernel<<<dim3(16, 16, 3), 256, 0, stream>>>(Wq, Wk, Wv, wqkvT);
  pack_wo_kernel<<<dim3(16, 16), 256, 0, stream>>>(Wo, woT);
  pack_bias_kernel<<<dim3(12), 256, 0, stream>>>(bq, bk, bv, bqkv);
  gemm_bt_kernel<0><<<dim3(24, 64), 256, 0, stream>>>(xb, wqkvT, bqkv, qB, kB, vB, nullptr);
  transpose_v_kernel<<<dim3(32, 64), 256, 0, stream>>>(vB, vT);
  flash_kernel<<<dim3(512), 256, 0, stream>>>(qB, kB, vT, zB);
  gemm_bt_kernel<1><<<dim3(8, 64), 256, 0, stream>>>(zB, woT, bo, nullptr, nullptr, nullptr, out);
}